// Round 6
// baseline (348.075 us; speedup 1.0000x reference)
//
#include <hip/hip_runtime.h>
#include <hip/hip_bf16.h>

// ModulatedConv2d (StyleGAN2): B=16, Cin=Cout=128, K=3, H=W=128, STYLE=512
// R9: back to the split structure (nhwc pre-transpose, conv = pure GEMM),
//     conv rebuilt on the counted-vmcnt pipeline (T3+T4+T5):
//     - xp gets zeroed guard ROWS (y=-1,128) in addition to guard cols,
//       so conv is a uniform 18-step K-loop (9 taps x 2 cin-halves), no
//       clamps, no tap skips.
//     - 128 cout x 256 px (2 y-rows) per block, 512 thr / 8 waves (2Mx4N),
//       A+B double-buffered (96 KB LDS, 1 block/CU).
//     - raw s_barrier + s_waitcnt vmcnt(6) (never 0 in the loop): stage(t+1)
//       stays in flight across the barrier, retiring behind a full MFMA
//       phase. sched_barrier(0) after lgkmcnt(0); setprio around MFMAs.

typedef __attribute__((ext_vector_type(8))) short short8;
typedef __attribute__((ext_vector_type(4))) float f32x4;

#define XPITCH (130 * 128)
#define CONV_SCALE 0.029462782549439483f /* 1/sqrt(128*9) */
#define LIN_SCALE 0.04419417382415922f   /* 1/sqrt(512) */

__device__ __forceinline__ void async16(unsigned short* lds, const unsigned short* g) {
  __builtin_amdgcn_global_load_lds((const __attribute__((address_space(1))) void*)g,
                                   (__attribute__((address_space(3))) void*)lds, 16, 0, 0);
}

__device__ __forceinline__ unsigned int pack2bf(float a, float b) {
  unsigned short ha = __builtin_bit_cast(unsigned short, __float2bfloat16(a));
  unsigned short hb = __builtin_bit_cast(unsigned short, __float2bfloat16(b));
  return (unsigned int)ha | ((unsigned int)hb << 16);
}

// s[b][cin] = sum_d style[b,d] * mod_w[cin,d] * LIN_SCALE + mod_b[cin]
__global__ void style_kernel(const float* __restrict__ style, const float* __restrict__ mod_w,
                             const float* __restrict__ mod_b, float* __restrict__ s_ws) {
  const int gw = blockIdx.x * 4 + (threadIdx.x >> 6);  // global wave 0..2047
  const int b = gw >> 7, cin = gw & 127, lane = threadIdx.x & 63;
  const float4 s0 = *(const float4*)(style + (size_t)b * 512 + lane * 4);
  const float4 s1 = *(const float4*)(style + (size_t)b * 512 + 256 + lane * 4);
  const float4 w0 = *(const float4*)(mod_w + (size_t)cin * 512 + lane * 4);
  const float4 w1 = *(const float4*)(mod_w + (size_t)cin * 512 + 256 + lane * 4);
  float acc = s0.x * w0.x + s0.y * w0.y + s0.z * w0.z + s0.w * w0.w +
              s1.x * w1.x + s1.y * w1.y + s1.z * w1.z + s1.w * w1.w;
#pragma unroll
  for (int off = 32; off; off >>= 1) acc += __shfl_xor(acc, off);
  if (lane == 0) s_ws[b * 128 + cin] = acc * LIN_SCALE + mod_b[cin];
}

// one block per (b, cout): wmod = CONV_SCALE*weight*s ; demod = rsqrt(sum wmod^2 + 1e-8)
// write bf16 w_ws[b][ky*3+kx][cout][cin]  (cin fastest, for A-tile staging)
__global__ void modw_kernel(const float* __restrict__ weight, const float* __restrict__ s_ws,
                            unsigned short* __restrict__ w_ws) {
  const int bid = blockIdx.x;
  const int b = bid >> 7, cout = bid & 127;
  const int cin = threadIdx.x;
  const float sv = s_ws[b * 128 + cin] * CONV_SCALE;
  const float* wp = weight + ((size_t)cout * 128 + cin) * 9;
  float v[9];
  float ss = 0.f;
#pragma unroll
  for (int j = 0; j < 9; ++j) { v[j] = wp[j] * sv; ss += v[j] * v[j]; }
#pragma unroll
  for (int off = 32; off; off >>= 1) ss += __shfl_down(ss, off);
  __shared__ float red[2];
  if ((threadIdx.x & 63) == 0) red[threadIdx.x >> 6] = ss;
  __syncthreads();
  const float dem = rsqrtf(red[0] + red[1] + 1e-8f);
#pragma unroll
  for (int j = 0; j < 9; ++j) {
    __hip_bfloat16 h = __float2bfloat16(v[j] * dem);
    w_ws[(((size_t)b * 9 + j) * 128 + cout) * 128 + cin] =
        __builtin_bit_cast(unsigned short, h);
  }
}

// x[b][cin][y][x] fp32 -> xp[b][row 0..129][xcol 0..129][cin] bf16,
// row = y+1, xcol = x+1; guard rows 0/129 and guard cols 0/129 are zero.
// Round-0's verified LDS-staged transpose (float4 loads, swizzled 8B LDS,
// 16B coalesced stores). grid = (130, 16): blockIdx.x = row, .y = b.
__global__ __launch_bounds__(256) void nhwc_kernel(const float* __restrict__ x,
                                                   unsigned short* __restrict__ xp) {
  const int b = blockIdx.y, row = blockIdx.x;
  const int tid = threadIdx.x;
  unsigned short* ob = xp + ((size_t)b * 130 + row) * XPITCH;
  if (row == 0 || row == 129) {  // guard row: zero 16640 ushort = 1040 uint4
    const uint4 z = {0u, 0u, 0u, 0u};
    for (int v = tid; v < 1040; v += 256) ((uint4*)ob)[v] = z;
    return;
  }
  const int y = row - 1;
  __shared__ unsigned short T[128 * 128];  // 32 KB
  const float* xb = x + (size_t)b * (128 * 16384) + y * 128;

  const int xc4 = tid & 31;   // float4 index along x
  const int cing = tid >> 5;  // 0..7
#pragma unroll
  for (int r = 0; r < 4; ++r) {
    const int cin0 = r * 32 + cing * 4;
    const int g = cin0 >> 2;  // logical 8B-group = cin/4
    float4 f[4];
#pragma unroll
    for (int j = 0; j < 4; ++j)
      f[j] = *(const float4*)(xb + (size_t)(cin0 + j) * 16384 + xc4 * 4);
#pragma unroll
    for (int i = 0; i < 4; ++i) {
      const int xc = xc4 * 4 + i;
      const int gp = g ^ (xc & 31);  // swizzled physical group in row xc
      uint2 col;
      col.x = pack2bf(((const float*)&f[0])[i], ((const float*)&f[1])[i]);
      col.y = pack2bf(((const float*)&f[2])[i], ((const float*)&f[3])[i]);
      *(uint2*)(&T[xc * 128 + gp * 4]) = col;
    }
  }
  __syncthreads();
#pragma unroll
  for (int rr = 0; rr < 8; ++rr) {
    const int v = rr * 256 + tid;
    const int cg = v & 15;  // 16B output group: cin = cg*8
    const int xc = v >> 4;  // 0..127
    const int s5 = xc & 31;
    const int g0 = (cg * 2) ^ s5, g1 = (cg * 2 + 1) ^ s5;
    const uint2 a = *(const uint2*)(&T[xc * 128 + g0 * 4]);
    const uint2 c = *(const uint2*)(&T[xc * 128 + g1 * 4]);
    uint4 o;
    o.x = a.x; o.y = a.y; o.z = c.x; o.w = c.y;
    *(uint4*)(ob + (xc + 1) * 128 + cg * 8) = o;
  }
  // zero guard cols: xcol 0 (x=-1) and xcol 129 (x=128)
  const uint4 z = {0u, 0u, 0u, 0u};
  if (tid < 16) *(uint4*)(ob + tid * 8) = z;
  else if (tid < 32) *(uint4*)(ob + 129 * 128 + (tid - 16) * 8) = z;
}

// one block per (b, y-pair): C[128 cout][256 px] (px = 2 y-rows x 128 x).
// 512 thr / 8 waves (2 cout-halves x 4 px-quarters), wave = 64x64 via
// 4x4 of 16x16x32 bf16 MFMA, 2 K-sub-steps per K-step (BK=64).
// K-steps t=0..17: tap j3 = t>>1, cin-half c0 = (t&1)*64.
__global__ __launch_bounds__(512, 2) void conv_kernel(const unsigned short* __restrict__ xp,
                                                      const unsigned short* __restrict__ wws,
                                                      float* __restrict__ out) {
  __shared__ unsigned short lA[2][128 * 64];  // 32 KB A dbuf
  __shared__ unsigned short lB[2][256 * 64];  // 64 KB B dbuf

  const int tid = threadIdx.x;
  // XCD-aware swizzle (1024 blocks, 1024%8==0 -> bijective)
  const int bid = (blockIdx.x & 7) * 128 + (blockIdx.x >> 3);
  const int b = bid >> 6, y0 = (bid & 63) * 2;
  const int lane = tid & 63, w = tid >> 6;
  const int wm = w & 1, wn = w >> 1;   // cout half, px quarter
  const int l15 = lane & 15, q = lane >> 4;

  f32x4 acc[4][4];
#pragma unroll
  for (int i = 0; i < 4; ++i)
#pragma unroll
    for (int t = 0; t < 4; ++t) acc[i][t] = (f32x4){0.f, 0.f, 0.f, 0.f};

  const unsigned short* xpb = xp + (size_t)b * 130 * XPITCH;
  const unsigned short* wb = wws + (size_t)b * 9 * 128 * 128;

  // A staging constants: chunk g = p*512+tid (p=0,1), m = g>>3, slot = g&7,
  // source chunk = slot ^ (m&7) (pre-swizzled source, linear LDS dest).
  const int am = tid >> 3;                                    // 0..63
  const unsigned short* asrc = wb + am * 128 + (((tid & 7) ^ (am & 7)) << 3);
  // B staging constants: 4 chunks, g = p*512+tid, n = g>>3 (px 0..255),
  // row = y0 + (n>>7) (+ky per step), xcol = n&127 (+kx per step).
  const unsigned short* bsrc[4];
#pragma unroll
  for (int p = 0; p < 4; ++p) {
    const int g = p * 512 + tid, n = g >> 3;
    const int c16 = (g & 7) ^ (n & 7);
    bsrc[p] = xpb + (size_t)(y0 + (n >> 7)) * XPITCH + (n & 127) * 128 + (c16 << 3);
  }
  const int dst8 = tid * 8;  // LDS dest (elems): +p*4096 per chunk

#define STAGE_STEP(cur_, j3_, ky_, kx_, c0_)                         \
  do {                                                               \
    const int ka = (j3_) * 16384 + (c0_);                            \
    async16(lA[cur_] + dst8, asrc + ka);                             \
    async16(lA[cur_] + 4096 + dst8, asrc + ka + 8192);               \
    const int kb = (ky_)*XPITCH + (kx_)*128 + (c0_);                 \
    async16(lB[cur_] + dst8, bsrc[0] + kb);                          \
    async16(lB[cur_] + 4096 + dst8, bsrc[1] + kb);                   \
    async16(lB[cur_] + 8192 + dst8, bsrc[2] + kb);                   \
    async16(lB[cur_] + 12288 + dst8, bsrc[3] + kb);                  \
  } while (0)

  // prologue: stage K-step 0 (tap 0, c0=0) into buffer 0
  STAGE_STEP(0, 0, 0, 0, 0);

#pragma unroll
  for (int t = 0; t < 18; ++t) {
    const int cur = t & 1;
    if (t < 17) {
      const int tn = t + 1;
      const int j3n = tn >> 1, c0n = (tn & 1) << 6;
      const int kyn = j3n / 3, kxn = j3n % 3;
      STAGE_STEP(cur ^ 1, j3n, kyn, kxn, c0n);
      asm volatile("s_waitcnt vmcnt(6)" ::: "memory");  // stage(t) landed (mine)
    } else {
      asm volatile("s_waitcnt vmcnt(0)" ::: "memory");
    }
    asm volatile("s_barrier" ::: "memory");  // stage(t) landed (all waves)

    short8 af[2][4], bf[2][4];
#pragma unroll
    for (int s = 0; s < 2; ++s) {
      const int axor = (((s * 4 + q) ^ (l15 & 7)) << 3);
#pragma unroll
      for (int i = 0; i < 4; ++i)
        af[s][i] = *(const short8*)(&lA[cur][(wm * 64 + i * 16 + l15) * 64 + axor]);
#pragma unroll
      for (int i = 0; i < 4; ++i)
        bf[s][i] = *(const short8*)(&lB[cur][(wn * 64 + i * 16 + l15) * 64 + axor]);
    }
    asm volatile("s_waitcnt lgkmcnt(0)" ::: "memory");
    __builtin_amdgcn_sched_barrier(0);  // rule #18: pin MFMAs after the wait
    __builtin_amdgcn_s_setprio(1);
#pragma unroll
    for (int s = 0; s < 2; ++s)
#pragma unroll
      for (int i = 0; i < 4; ++i)
#pragma unroll
        for (int u = 0; u < 4; ++u)
          acc[i][u] = __builtin_amdgcn_mfma_f32_16x16x32_bf16(af[s][i], bf[s][u], acc[i][u], 0, 0, 0);
    __builtin_amdgcn_s_setprio(0);
    asm volatile("s_barrier" ::: "memory");  // all waves done reading buf[cur]
  }
#undef STAGE_STEP

  // C/D layout: col(px) = lane&15, row(cout) = (lane>>4)*4 + reg
  // px n = wn*64 + t*16 + l15 -> y = y0 + (wn>>1), x = (wn&1)*64 + t*16 + l15
  float* obase = out + (size_t)b * (128 * 16384) + (y0 + (wn >> 1)) * 128 + (wn & 1) * 64;
#pragma unroll
  for (int i = 0; i < 4; ++i) {
    const int coutb = wm * 64 + i * 16 + q * 4;
#pragma unroll
    for (int rr = 0; rr < 4; ++rr) {
      float* orow = obase + (size_t)(coutb + rr) * 16384;
#pragma unroll
      for (int t = 0; t < 4; ++t) orow[t * 16 + l15] = acc[i][t][rr];
    }
  }
}

extern "C" void kernel_launch(void* const* d_in, const int* in_sizes, int n_in,
                              void* d_out, int out_size, void* d_ws, size_t ws_size,
                              hipStream_t stream) {
  const float* x = (const float*)d_in[0];
  const float* style = (const float*)d_in[1];
  const float* weight = (const float*)d_in[2];
  const float* mod_w = (const float*)d_in[3];
  const float* mod_b = (const float*)d_in[4];
  float* out = (float*)d_out;

  char* ws = (char*)d_ws;
  float* s_ws = (float*)ws;                                  // 8 KB
  unsigned short* w_ws = (unsigned short*)(ws + 8192);       // 4.5 MB
  unsigned short* xp = (unsigned short*)(ws + (5u << 20));   // 69.3 MB (130 rows incl guards)

  style_kernel<<<512, 256, 0, stream>>>(style, mod_w, mod_b, s_ws);
  modw_kernel<<<16 * 128, 128, 0, stream>>>(weight, s_ws, w_ws);
  nhwc_kernel<<<dim3(130, 16), 256, 0, stream>>>(x, xp);
  conv_kernel<<<16 * 64, 512, 0, stream>>>(xp, w_ws, out);
}

// Round 7
// 329.786 us; speedup vs baseline: 1.0555x; 1.0555x over previous
//
#include <hip/hip_runtime.h>
#include <hip/hip_bf16.h>

// ModulatedConv2d (StyleGAN2): B=16, Cin=Cout=128, K=3, H=W=128, STYLE=512
// R10: (a) modulation folded into x (nhwc multiplies by s[b,cin]), demod
//      folded into conv epilogue -> weights are batch-shared (294 KB,
//      L2-resident); modw_kernel replaced by tiny wprep + demod matvec.
//      (b) conv: BK=32, 3-deep A+B pipeline (72 KB LDS -> 2 blocks/CU =
//      16 waves/CU), counted s_waitcnt vmcnt(6), paired-row XOR-swizzled
//      LDS layout (conflict-free b128 reads at BK=32).

typedef __attribute__((ext_vector_type(8))) short short8;
typedef __attribute__((ext_vector_type(4))) float f32x4;

#define XPITCH (130 * 128)
#define CONV_SCALE 0.029462782549439483f /* 1/sqrt(128*9) */
#define LIN_SCALE 0.04419417382415922f   /* 1/sqrt(512) */

__device__ __forceinline__ void async16(unsigned short* lds, const unsigned short* g) {
  __builtin_amdgcn_global_load_lds((const __attribute__((address_space(1))) void*)g,
                                   (__attribute__((address_space(3))) void*)lds, 16, 0, 0);
}

__device__ __forceinline__ unsigned int pack2bf(float a, float b) {
  unsigned short ha = __builtin_bit_cast(unsigned short, __float2bfloat16(a));
  unsigned short hb = __builtin_bit_cast(unsigned short, __float2bfloat16(b));
  return (unsigned int)ha | ((unsigned int)hb << 16);
}

// s[b][cin] = sum_d style[b,d] * mod_w[cin,d] * LIN_SCALE + mod_b[cin]
__global__ void style_kernel(const float* __restrict__ style, const float* __restrict__ mod_w,
                             const float* __restrict__ mod_b, float* __restrict__ s_ws) {
  const int gw = blockIdx.x * 4 + (threadIdx.x >> 6);  // global wave 0..2047
  const int b = gw >> 7, cin = gw & 127, lane = threadIdx.x & 63;
  const float4 s0 = *(const float4*)(style + (size_t)b * 512 + lane * 4);
  const float4 s1 = *(const float4*)(style + (size_t)b * 512 + 256 + lane * 4);
  const float4 w0 = *(const float4*)(mod_w + (size_t)cin * 512 + lane * 4);
  const float4 w1 = *(const float4*)(mod_w + (size_t)cin * 512 + 256 + lane * 4);
  float acc = s0.x * w0.x + s0.y * w0.y + s0.z * w0.z + s0.w * w0.w +
              s1.x * w1.x + s1.y * w1.y + s1.z * w1.z + s1.w * w1.w;
#pragma unroll
  for (int off = 32; off; off >>= 1) acc += __shfl_xor(acc, off);
  if (lane == 0) s_ws[b * 128 + cin] = acc * LIN_SCALE + mod_b[cin];
}

// batch-shared weight prep: wsh[tap][cout][cin] = bf16(CONV_SCALE * w),
// W2[cout][cin] = CONV_SCALE^2 * sum_k w^2  (for the demod matvec)
__global__ void wprep_kernel(const float* __restrict__ weight,
                             unsigned short* __restrict__ wsh, float* __restrict__ W2) {
  const int cout = blockIdx.x, cin = threadIdx.x;
  const float* wp = weight + ((size_t)cout * 128 + cin) * 9;
  float ss = 0.f;
#pragma unroll
  for (int j = 0; j < 9; ++j) {
    const float v = wp[j] * CONV_SCALE;
    ss += v * v;
    wsh[j * 16384 + cout * 128 + cin] =
        __builtin_bit_cast(unsigned short, __float2bfloat16(v));
  }
  W2[cout * 128 + cin] = ss;
}

// demod[b][cout] = rsqrt( sum_cin W2[cout][cin] * s[b][cin]^2 + 1e-8 )
__global__ void demod_kernel(const float* __restrict__ W2, const float* __restrict__ s_ws,
                             float* __restrict__ d_ws) {
  const int gw = blockIdx.x * 4 + (threadIdx.x >> 6);  // 0..2047
  const int b = gw >> 7, cout = gw & 127, lane = threadIdx.x & 63;
  const float2 w2 = *(const float2*)(W2 + cout * 128 + lane * 2);
  const float2 sv = *(const float2*)(s_ws + b * 128 + lane * 2);
  float acc = w2.x * sv.x * sv.x + w2.y * sv.y * sv.y;
#pragma unroll
  for (int off = 32; off; off >>= 1) acc += __shfl_xor(acc, off);
  if (lane == 0) d_ws[b * 128 + cout] = rsqrtf(acc + 1e-8f);
}

// x[b][cin][y][x] fp32 -> xp[b][row 0..129][xcol 0..129][cin] bf16 of x*s,
// row = y+1, xcol = x+1; guard rows 0/129 and cols 0/129 zero.
__global__ __launch_bounds__(256) void nhwc_kernel(const float* __restrict__ x,
                                                   const float* __restrict__ s_ws,
                                                   unsigned short* __restrict__ xp) {
  const int b = blockIdx.y, row = blockIdx.x;
  const int tid = threadIdx.x;
  unsigned short* ob = xp + ((size_t)b * 130 + row) * XPITCH;
  if (row == 0 || row == 129) {  // guard row
    const uint4 z = {0u, 0u, 0u, 0u};
    for (int v = tid; v < 1040; v += 256) ((uint4*)ob)[v] = z;
    return;
  }
  const int y = row - 1;
  __shared__ unsigned short T[128 * 128];  // 32 KB
  const float* xb = x + (size_t)b * (128 * 16384) + y * 128;

  const int xc4 = tid & 31;   // float4 index along x
  const int cing = tid >> 5;  // 0..7
#pragma unroll
  for (int r = 0; r < 4; ++r) {
    const int cin0 = r * 32 + cing * 4;
    const int g = cin0 >> 2;
    const float4 sv = *(const float4*)(s_ws + b * 128 + cin0);
    float4 f[4];
#pragma unroll
    for (int j = 0; j < 4; ++j) {
      f[j] = *(const float4*)(xb + (size_t)(cin0 + j) * 16384 + xc4 * 4);
      const float s = ((const float*)&sv)[j];
      f[j].x *= s; f[j].y *= s; f[j].z *= s; f[j].w *= s;
    }
#pragma unroll
    for (int i = 0; i < 4; ++i) {
      const int xc = xc4 * 4 + i;
      const int gp = g ^ (xc & 31);
      uint2 col;
      col.x = pack2bf(((const float*)&f[0])[i], ((const float*)&f[1])[i]);
      col.y = pack2bf(((const float*)&f[2])[i], ((const float*)&f[3])[i]);
      *(uint2*)(&T[xc * 128 + gp * 4]) = col;
    }
  }
  __syncthreads();
#pragma unroll
  for (int rr = 0; rr < 8; ++rr) {
    const int v = rr * 256 + tid;
    const int cg = v & 15;
    const int xc = v >> 4;
    const int s5 = xc & 31;
    const int g0 = (cg * 2) ^ s5, g1 = (cg * 2 + 1) ^ s5;
    const uint2 a = *(const uint2*)(&T[xc * 128 + g0 * 4]);
    const uint2 c = *(const uint2*)(&T[xc * 128 + g1 * 4]);
    uint4 o;
    o.x = a.x; o.y = a.y; o.z = c.x; o.w = c.y;
    *(uint4*)(ob + (xc + 1) * 128 + cg * 8) = o;
  }
  const uint4 z = {0u, 0u, 0u, 0u};
  if (tid < 16) *(uint4*)(ob + tid * 8) = z;
  else if (tid < 32) *(uint4*)(ob + 129 * 128 + (tid - 16) * 8) = z;
}

// one block per (b, y-pair): C[128 cout][256 px]. 512 thr / 8 waves (2x4),
// wave = 64x64 via 4x4 MFMA 16x16x32. BK=32 -> 36 K-steps (tap = t>>2,
// c0 = (t&3)*32). 3-deep pipeline: stage(t+2) issued at iter t; steady
// state waits vmcnt(6) (= stage(t) landed, 2 stages in flight).
// LDS paired-row layout: LDS row r (128 B, 8 chunks) holds m = {2r, 2r+1};
// chunk_phys = ((m&1)*4 + kq) ^ (r&7), kq = k/8. Quarter-wave reads hit
// each 16B slot exactly twice -> conflict-free.
__global__ __launch_bounds__(512, 2) void conv_kernel(const unsigned short* __restrict__ xp,
                                                      const unsigned short* __restrict__ wsh,
                                                      const float* __restrict__ d_ws,
                                                      float* __restrict__ out) {
  __shared__ unsigned short lA[3][4096];  // 3 x 8 KB  (128 m x 32 k)
  __shared__ unsigned short lB[3][8192];  // 3 x 16 KB (256 n x 32 k)

  const int tid = threadIdx.x;
  // XCD-aware swizzle (1024 blocks, bijective)
  const int bid = (blockIdx.x & 7) * 128 + (blockIdx.x >> 3);
  const int b = bid >> 6, y0 = (bid & 63) * 2;
  const int lane = tid & 63, w = tid >> 6;
  const int wm = w & 1, wn = w >> 1;  // cout half, px quarter
  const int l15 = lane & 15, q = lane >> 4;

  f32x4 acc[4][4];
#pragma unroll
  for (int i = 0; i < 4; ++i)
#pragma unroll
    for (int t = 0; t < 4; ++t) acc[i][t] = (f32x4){0.f, 0.f, 0.f, 0.f};

  const unsigned short* xpb = xp + (size_t)b * 130 * XPITCH;

  // A staging: one 16B chunk per thread, c = tid.
  const int ar = tid >> 3, ap = tid & 7;
  const int alog = ap ^ (ar & 7);
  const unsigned short* asrc = wsh + (ar * 2 + (alog >> 2)) * 128 + (alog & 3) * 8;
  // B staging: two chunks per thread, c = p*512 + tid.
  const unsigned short* bsrc[2];
#pragma unroll
  for (int p = 0; p < 2; ++p) {
    const int c = p * 512 + tid;
    const int r = c >> 3, ph = c & 7, lg = ph ^ (r & 7);
    const int n = r * 2 + (lg >> 2), kq = lg & 3;
    bsrc[p] = xpb + (size_t)(y0 + (n >> 7)) * XPITCH + (n & 127) * 128 + kq * 8;
  }
  const int dst8 = tid * 8;  // ushort offset of this thread's chunk

  // read offsets: phys independent of i/u (r&7 = l15>>1 for all blocks)
  const int phys = (((l15 & 1) << 2) | q) ^ (l15 >> 1);
  const int aoff = (wm * 32 + (l15 >> 1)) * 64 + phys * 8;
  const int boff = (wn * 32 + (l15 >> 1)) * 64 + phys * 8;

#define STAGE(buf_, tap_, ky_, kx_, c0_)                              \
  do {                                                                \
    async16(lA[buf_] + dst8, asrc + (tap_) * 16384 + (c0_));          \
    const int kb_ = (ky_)*XPITCH + (kx_)*128 + (c0_);                 \
    async16(lB[buf_] + dst8, bsrc[0] + kb_);                          \
    async16(lB[buf_] + 4096 + dst8, bsrc[1] + kb_);                   \
  } while (0)

  // prologue: stage K-steps 0 and 1
  STAGE(0, 0, 0, 0, 0);
  STAGE(1, 0, 0, 0, 32);

#pragma unroll
  for (int t = 0; t < 36; ++t) {
    const int cur = t % 3;
    if (t < 34) {
      const int tn = t + 2, tap = tn >> 2, c0 = (tn & 3) * 32;
      const int ky = tap / 3, kx = tap % 3;
      STAGE((tn) % 3, tap, ky, kx, c0);
      asm volatile("s_waitcnt vmcnt(6)" ::: "memory");  // stage(t) landed
    } else if (t == 34) {
      asm volatile("s_waitcnt vmcnt(3)" ::: "memory");
    } else {
      asm volatile("s_waitcnt vmcnt(0)" ::: "memory");
    }
    asm volatile("s_barrier" ::: "memory");  // stage(t) visible to all waves

    short8 af[4], bf[4];
#pragma unroll
    for (int i = 0; i < 4; ++i) af[i] = *(const short8*)(&lA[cur][aoff + i * 512]);
#pragma unroll
    for (int u = 0; u < 4; ++u) bf[u] = *(const short8*)(&lB[cur][boff + u * 512]);
    asm volatile("s_waitcnt lgkmcnt(0)" ::: "memory");
    __builtin_amdgcn_sched_barrier(0);  // rule #18
    __builtin_amdgcn_s_setprio(1);
#pragma unroll
    for (int i = 0; i < 4; ++i)
#pragma unroll
      for (int u = 0; u < 4; ++u)
        acc[i][u] = __builtin_amdgcn_mfma_f32_16x16x32_bf16(af[i], bf[u], acc[i][u], 0, 0, 0);
    __builtin_amdgcn_s_setprio(0);
    if (t < 35) asm volatile("s_barrier" ::: "memory");  // buf[cur] free for restage
  }
#undef STAGE

  // epilogue: apply demod[b][cout], write out.
  // C/D layout: col(px) = lane&15, row(cout) = (lane>>4)*4 + reg
  float dmv[4][4];
#pragma unroll
  for (int i = 0; i < 4; ++i)
#pragma unroll
    for (int rr = 0; rr < 4; ++rr)
      dmv[i][rr] = d_ws[b * 128 + wm * 64 + i * 16 + q * 4 + rr];

  float* obase = out + (size_t)b * (128 * 16384) + (y0 + (wn >> 1)) * 128 + (wn & 1) * 64;
#pragma unroll
  for (int i = 0; i < 4; ++i) {
    const int coutb = wm * 64 + i * 16 + q * 4;
#pragma unroll
    for (int rr = 0; rr < 4; ++rr) {
      float* orow = obase + (size_t)(coutb + rr) * 16384;
#pragma unroll
      for (int t = 0; t < 4; ++t) orow[t * 16 + l15] = acc[i][t][rr] * dmv[i][rr];
    }
  }
}

extern "C" void kernel_launch(void* const* d_in, const int* in_sizes, int n_in,
                              void* d_out, int out_size, void* d_ws, size_t ws_size,
                              hipStream_t stream) {
  const float* x = (const float*)d_in[0];
  const float* style = (const float*)d_in[1];
  const float* weight = (const float*)d_in[2];
  const float* mod_w = (const float*)d_in[3];
  const float* mod_b = (const float*)d_in[4];
  float* out = (float*)d_out;

  char* ws = (char*)d_ws;
  float* s_ws = (float*)ws;                                  // 8 KB
  float* d_dm = (float*)(ws + 8192);                         // 8 KB
  float* W2 = (float*)(ws + 16384);                          // 64 KB
  unsigned short* wsh = (unsigned short*)(ws + 81920);       // 288 KB
  unsigned short* xp = (unsigned short*)(ws + (1u << 20));   // 69.2 MB

  style_kernel<<<512, 256, 0, stream>>>(style, mod_w, mod_b, s_ws);
  wprep_kernel<<<128, 128, 0, stream>>>(weight, wsh, W2);
  nhwc_kernel<<<dim3(130, 16), 256, 0, stream>>>(x, s_ws, xp);
  demod_kernel<<<512, 256, 0, stream>>>(W2, s_ws, d_dm);
  conv_kernel<<<16 * 64, 512, 0, stream>>>(xp, wsh, d_dm, out);
}